// Round 1
// 450.476 us; speedup vs baseline: 1.1755x; 1.1755x over previous
//
#include <hip/hip_runtime.h>

#define N_ROWS 32768
#define DIMS 256
#define K_CODES 1024
#define MT 32      // rows per block (fused kernel)
#define NCHUNK 128 // codes per chunk
#define KC 32      // K per LDS stage

static constexpr size_t SC_OFF  = 8388608;   // after quantized [32768*256] (float32 elements)
static constexpr size_t IDX_OFF = 8388612;   // after 4 scalars

__device__ inline float wsum64(float v){
  #pragma unroll
  for(int off=32; off; off>>=1) v += __shfl_xor(v, off, 64);
  return v;
}

// ---- row squared norms: bit-exact numpy AVX512 SIMD pairwise emulation -----
// np.sum(a*a, -1), n=256: pairwise split 128+128. Each 128-block (numpy
// loops_arithm_fp dispatch, AVX512, nlanes=16): 8 vector accumulators
// r_j = a[16j..16j+15]; lanewise combine ((r0+r1)+(r2+r3))+((r4+r5)+(r6+r7));
// then _mm512_reduce_add_ps butterfly: (+8)(+4)(+2)(+1). Squares rounded
// before summing; __fmul_rn/__fadd_rn forbid FMA contraction.
__global__ __launch_bounds__(256) void rowsq_np512_kernel(const float* __restrict__ X,
                                                          const float* __restrict__ CB,
                                                          float* __restrict__ xsq,
                                                          float* __restrict__ csq){
  int r = blockIdx.x*256 + threadIdx.x;   // 0..33791
  if(r >= K_CODES + N_ROWS) return;
  const float* src; float* dst;
  if(r < K_CODES){ src = CB + (size_t)r*DIMS; dst = csq + r; }
  else { src = X + (size_t)(r - K_CODES)*DIMS; dst = xsq + (r - K_CODES); }

  float blk[2];
  #pragma unroll
  for(int bb=0; bb<2; bb++){
    const float* s = src + bb*128;
    float q[128];
    #pragma unroll
    for(int i=0;i<32;i++){
      float4 v = *(const float4*)(s + i*4);
      q[i*4+0]=__fmul_rn(v.x,v.x); q[i*4+1]=__fmul_rn(v.y,v.y);
      q[i*4+2]=__fmul_rn(v.z,v.z); q[i*4+3]=__fmul_rn(v.w,v.w);
    }
    float v16[16];
    #pragma unroll
    for(int l=0;l<16;l++)
      v16[l] = __fadd_rn(__fadd_rn(__fadd_rn(q[l],     q[l+16]),
                                   __fadd_rn(q[l+32],  q[l+48])),
                         __fadd_rn(__fadd_rn(q[l+64],  q[l+80]),
                                   __fadd_rn(q[l+96],  q[l+112])));
    float w8[8];
    #pragma unroll
    for(int l=0;l<8;l++) w8[l] = __fadd_rn(v16[l], v16[l+8]);
    float u4[4];
    #pragma unroll
    for(int l=0;l<4;l++) u4[l] = __fadd_rn(w8[l], w8[l+4]);
    float t0 = __fadd_rn(u4[0], u4[2]);
    float t1 = __fadd_rn(u4[1], u4[3]);
    blk[bb] = __fadd_rn(t0, t1);
  }
  *dst = __fadd_rn(blk[0], blk[1]);
}

// --------- fused: distances + argmin + online softmax + quant gather --------
// Changes vs prior version:
//  (1) striped code ownership: thread tx owns codes {tx*4+0..3, 64+tx*4+0..3}
//      -> both ds_read_b128 of Bs cover a contiguous 256B window across the
//      16 tx lanes = 2 addresses/bank = conflict-free (was 4-way, 7.8e7 cyc).
//  (2) register prefetch of next stage's global loads, issued after the
//      post-write barrier so L2 latency hides under the 1024-cycle FMA phase.
//  (3) quant gather + mse fused into the epilogue (km broadcast via LDS).
// The per-(row,code) single-accumulator ascending-k fmaf chain is unchanged
// -> distances remain bit-exact vs the CPU BLAS reference.
__global__ __launch_bounds__(256,4) void fused_argmin_kernel(
    const float* __restrict__ X, const float* __restrict__ CB,
    const float* __restrict__ xsq, const float* __restrict__ csq,
    float* __restrict__ hist, float* __restrict__ acc_sc,
    float* __restrict__ out)
{
  __shared__ float As[KC][34];      // stride 34: 8B-aligned float2 reads, conflict-free
  __shared__ float Bs[KC][NCHUNK];
  __shared__ int   sk[MT];          // argmin index broadcast for the gather phase
  const int t  = threadIdx.x;
  const int tx = t & 15, ty = t >> 4;
  const int m0 = blockIdx.x * MT;

  // per-thread online state for rows ty*2 + {0,1} (replicated across the 16 tx lanes)
  float dm[2]; int km[2]; float Ss[2], Ts[2];

  const float xs0 = xsq[m0 + ty*2];
  const float xs1 = xsq[m0 + ty*2 + 1];

  const int arow = t >> 3;          // 0..31 : row within tile
  const int acol = (t & 7) * 4;     // 0..28 : k offset
  const float* Ag = X + (size_t)(m0 + arow)*DIMS + acol;
  const int brow = t >> 1;          // 0..127 : code within chunk
  const int bcol = (t & 1) * 16;    // 0/16   : k offset

  // stage-0 register prefetch
  float4 a4 = *(const float4*)(Ag);
  float4 b4[4];
  {
    const float* Bg0 = CB + (size_t)brow*DIMS + bcol;
    #pragma unroll
    for(int q=0;q<4;q++) b4[q] = *(const float4*)(Bg0 + q*4);
  }

  for(int nc=0; nc<8; nc++){
    const int n0c = nc*NCHUNK;
    const float* Bg = CB + (size_t)(n0c + brow)*DIMS + bcol;
    float acc[2][8];
    #pragma unroll
    for(int i=0;i<2;i++)
      #pragma unroll
      for(int j=0;j<8;j++) acc[i][j]=0.f;

    // K-chain: strictly ascending k=0..255, one fmaf chain per (row,code) —
    // matches BLAS sgemm's single-accumulator ascending-k FMA microkernel.
    for(int kc=0;kc<8;kc++){
      __syncthreads();
      // commit prefetched stage to LDS
      As[acol+0][arow]=a4.x; As[acol+1][arow]=a4.y;
      As[acol+2][arow]=a4.z; As[acol+3][arow]=a4.w;
      #pragma unroll
      for(int q=0;q<4;q++){
        Bs[bcol+q*4+0][brow]=b4[q].x; Bs[bcol+q*4+1][brow]=b4[q].y;
        Bs[bcol+q*4+2][brow]=b4[q].z; Bs[bcol+q*4+3][brow]=b4[q].w;
      }
      __syncthreads();
      // prefetch next stage (kc+1 of this chunk, or stage 0 of the next chunk);
      // latency hides under the 512-FMA compute phase below.
      {
        const float* An = Ag + ((kc+1)&7)*KC;
        const float* Bn = (kc < 7) ? (Bg + (kc+1)*KC)
                                   : (CB + (size_t)((((nc+1)&7)*NCHUNK) + brow)*DIMS + bcol);
        a4 = *(const float4*)An;
        #pragma unroll
        for(int q=0;q<4;q++) b4[q] = *(const float4*)(Bn + q*4);
      }
      #pragma unroll
      for(int k=0;k<KC;k++){
        float2 a2 = *(const float2*)&As[k][ty*2];
        // striped: codes tx*4+{0..3} and 64+tx*4+{0..3} — contiguous 256B per read
        float4 b0 = *(const float4*)&Bs[k][tx*4];
        float4 b1 = *(const float4*)&Bs[k][64 + tx*4];
        float bv[8]={b0.x,b0.y,b0.z,b0.w,b1.x,b1.y,b1.z,b1.w};
        #pragma unroll
        for(int j=0;j<8;j++){
          acc[0][j] = fmaf(a2.x, bv[j], acc[0][j]);
          acc[1][j] = fmaf(a2.y, bv[j], acc[1][j]);
        }
      }
    }

    // ---- chunk epilogue: d = sqrt(max(fl(fl(xs+cs) - 2*dot), 0)) -----------
    float csv[8];
    { float4 c0 = *(const float4*)(csq + n0c + tx*4);
      float4 c1 = *(const float4*)(csq + n0c + 64 + tx*4);
      csv[0]=c0.x; csv[1]=c0.y; csv[2]=c0.z; csv[3]=c0.w;
      csv[4]=c1.x; csv[5]=c1.y; csv[6]=c1.z; csv[7]=c1.w; }
    #pragma unroll
    for(int i=0;i<2;i++){
      float xs = i ? xs1 : xs0;
      float d[8];
      #pragma unroll
      for(int j=0;j<8;j++){
        // contraction-safe: 2*acc exact, fma(-2,acc,t) == fl(t - 2*acc)
        float d2 = (xs + csv[j]) - 2.0f*acc[i][j];
        d[j] = sqrtf(fmaxf(d2, 0.f));
      }
      // thread-local argmin, ascending kidx, strict < (first-occurrence tie)
      float dl = INFINITY; int kl = 0;
      #pragma unroll
      for(int j=0;j<8;j++){
        int kidx = n0c + (j>>2)*64 + tx*4 + (j&3);   // ascending in j
        if(d[j] < dl){ dl = d[j]; kl = kidx; }
      }
      // butterfly across the 16 tx lanes of this row group
      #pragma unroll
      for(int off=1; off<16; off<<=1){
        float od = __shfl_xor(dl, off, 64);
        int   ok = __shfl_xor(kl, off, 64);
        if(od < dl || (od == dl && ok < kl)){ dl = od; kl = ok; }
      }
      // chunk softmax stats shifted at chunk min: l = (dl - d)*100 <= 0
      float s1=0.f, t2s=0.f;
      #pragma unroll
      for(int j=0;j<8;j++){
        float l = (dl - d[j])*100.0f;
        float e = expf(l);
        s1 += e; t2s = fmaf(e, l, t2s);
      }
      #pragma unroll
      for(int off=1; off<16; off<<=1){
        s1  += __shfl_xor(s1,  off, 64);
        t2s += __shfl_xor(t2s, off, 64);
      }
      if(nc == 0){
        dm[i]=dl; km[i]=kl; Ss[i]=s1; Ts[i]=t2s;
      } else {
        if(dl < dm[i]){                      // strict <: tie keeps old (smaller idx)
          float del = 100.0f*(dl - dm[i]); float al = expf(del);
          Ts[i] = al*(Ts[i] + Ss[i]*del) + t2s;
          Ss[i] = al*Ss[i] + s1;
          dm[i] = dl; km[i] = kl;
        } else {
          float del = 100.0f*(dm[i] - dl); float al = expf(del);
          Ts[i] += al*(t2s + s1*del);
          Ss[i] += al*s1;
        }
      }
    }
  }

  // ---- final per-row writes (one owner thread per row group: tx==0)
  float plogp = 0.f;
  if(tx == 0){
    #pragma unroll
    for(int i=0;i<2;i++){
      int n = m0 + ty*2 + i;
      out[IDX_OFF + n] = (float)km[i];
      sk[ty*2 + i] = km[i];
      atomicAdd(hist + km[i], 1.0f);
      plogp += Ts[i]/Ss[i] - logf(Ss[i]);
    }
  }
  plogp = wsum64(plogp);
  if((t & 63) == 0) atomicAdd(acc_sc + 1, plogp);

  // ---- fused quant gather + mse (was quant_kernel) -------------------------
  __syncthreads();                 // sk[] visible to all waves
  {
    int w = t>>6, lane = t&63;
    int row0 = w*8;
    float mse = 0.f;
    #pragma unroll
    for(int r=0;r<8;r++){
      int n = m0 + row0 + r;
      int k = sk[row0 + r];
      float4 cb4 = *(const float4*)(CB + (size_t)k*DIMS + lane*4);
      float4 x4  = *(const float4*)(X  + (size_t)n*DIMS + lane*4);
      float e0=x4.x-cb4.x, e1=x4.y-cb4.y, e2=x4.z-cb4.z, e3=x4.w-cb4.w;
      mse += e0*e0 + e1*e1 + e2*e2 + e3*e3;
      *reinterpret_cast<float4*>(out + (size_t)n*DIMS + lane*4) = cb4;
    }
    mse = wsum64(mse);
    if(lane==0) atomicAdd(acc_sc+0, mse);
  }
}

// ---------------- finalize scalars (float32) --------------------------------
__global__ __launch_bounds__(256) void finalize_kernel(const float* __restrict__ hist,
                                                       const float* __restrict__ acc_sc,
                                                       float* __restrict__ out){
  __shared__ float red[256];
  int t = threadIdx.x;
  float s = 0.f;
  #pragma unroll
  for(int c=0;c<4;c++){
    float ap = hist[c*256 + t] * (1.0f/32768.0f);   // avg_probs ~ argmin histogram
    s += ap * logf(ap + 1e-5f);
  }
  red[t] = s; __syncthreads();
  for(int off=128; off; off>>=1){
    if(t<off) red[t]+=red[t+off];
    __syncthreads();
  }
  if(t==0){
    float avg_entropy    = -red[0];
    float mse            = acc_sc[0] * (1.0f/8388608.0f);
    float sample_entropy = -(acc_sc[1] * (1.0f/32768.0f));
    float commit = 0.5f*mse*0.25f;
    float cbl    = 0.5f*mse;
    float ent    = (sample_entropy - avg_entropy)*0.1f;
    float vq     = cbl + commit + ent;
    out[SC_OFF+0] = vq;
    out[SC_OFF+1] = commit;
    out[SC_OFF+2] = cbl;
    out[SC_OFF+3] = ent;
  }
}

extern "C" void kernel_launch(void* const* d_in, const int* in_sizes, int n_in,
                              void* d_out, int out_size, void* d_ws, size_t ws_size,
                              hipStream_t stream){
  const float* X  = (const float*)d_in[0];
  const float* CB = (const float*)d_in[1];
  float* out = (float*)d_out;                        // float32 output buffer
  // ws layout (~270 KB total; kmin slot retained but unused now)
  float* xsq     = (float*)d_ws + N_ROWS;            // [32768]
  float* csq     = xsq + N_ROWS;                     // [1024]
  float* hist    = csq + K_CODES;                    // [1024]
  float* acc_sc  = hist + K_CODES;                   // [2]: mse, plogp

  hipMemsetAsync(hist, 0, (K_CODES+2)*sizeof(float), stream);
  rowsq_np512_kernel <<<(K_CODES+N_ROWS+255)/256, 256, 0, stream>>>(X, CB, xsq, csq);
  fused_argmin_kernel<<<N_ROWS/MT, 256, 0, stream>>>(X, CB, xsq, csq, hist, acc_sc, out);
  finalize_kernel    <<<1, 256, 0, stream>>>(hist, acc_sc, out);
}

// Round 2
// 393.289 us; speedup vs baseline: 1.3464x; 1.1454x over previous
//
#include <hip/hip_runtime.h>

#define N_ROWS 32768
#define DIMS 256
#define K_CODES 1024
#define MT 64      // rows per block (fused kernel)
#define NCHUNK 256 // codes per chunk
#define KC 32      // K per LDS stage
#define SA 68      // As stride: 64 rows + 4 pad (16B-aligned, conflict-free reads)
#define SB 260     // Bs stride: 256 codes + 4 pad (16B-aligned, conflict-free reads)

static constexpr size_t SC_OFF  = 8388608;   // after quantized [32768*256] (float32 elements)
static constexpr size_t IDX_OFF = 8388612;   // after 4 scalars

__device__ inline float wsum64(float v){
  #pragma unroll
  for(int off=32; off; off>>=1) v += __shfl_xor(v, off, 64);
  return v;
}

// ---- row squared norms: bit-exact numpy AVX512 SIMD pairwise emulation -----
__global__ __launch_bounds__(256) void rowsq_np512_kernel(const float* __restrict__ X,
                                                          const float* __restrict__ CB,
                                                          float* __restrict__ xsq,
                                                          float* __restrict__ csq){
  int r = blockIdx.x*256 + threadIdx.x;   // 0..33791
  if(r >= K_CODES + N_ROWS) return;
  const float* src; float* dst;
  if(r < K_CODES){ src = CB + (size_t)r*DIMS; dst = csq + r; }
  else { src = X + (size_t)(r - K_CODES)*DIMS; dst = xsq + (r - K_CODES); }

  float blk[2];
  #pragma unroll
  for(int bb=0; bb<2; bb++){
    const float* s = src + bb*128;
    float q[128];
    #pragma unroll
    for(int i=0;i<32;i++){
      float4 v = *(const float4*)(s + i*4);
      q[i*4+0]=__fmul_rn(v.x,v.x); q[i*4+1]=__fmul_rn(v.y,v.y);
      q[i*4+2]=__fmul_rn(v.z,v.z); q[i*4+3]=__fmul_rn(v.w,v.w);
    }
    float v16[16];
    #pragma unroll
    for(int l=0;l<16;l++)
      v16[l] = __fadd_rn(__fadd_rn(__fadd_rn(q[l],     q[l+16]),
                                   __fadd_rn(q[l+32],  q[l+48])),
                         __fadd_rn(__fadd_rn(q[l+64],  q[l+80]),
                                   __fadd_rn(q[l+96],  q[l+112])));
    float w8[8];
    #pragma unroll
    for(int l=0;l<8;l++) w8[l] = __fadd_rn(v16[l], v16[l+8]);
    float u4[4];
    #pragma unroll
    for(int l=0;l<4;l++) u4[l] = __fadd_rn(w8[l], w8[l+4]);
    float t0 = __fadd_rn(u4[0], u4[2]);
    float t1 = __fadd_rn(u4[1], u4[3]);
    blk[bb] = __fadd_rn(t0, t1);
  }
  *dst = __fadd_rn(blk[0], blk[1]);
}

// --------- fused: distances + argmin + online softmax + quant gather --------
// LDS-bandwidth-driven redesign:
//  * 4 rows x 16 codes per thread (was 2x8): per k, 1 b128 (A) + 4 b128 (B)
//    = 80 B LDS for 64 FMAs (1.25 B/FMA, was 2.5) -> LDS-bound ceiling ~2x lower.
//  * k-major LDS tiles As[k][row], Bs[k][code]: all inner-loop reads are
//    contiguous float4 with bank-start (4k+4ty|4tx)%32 -> <=2-way (free).
//    Staging writes are b32 scatters: B conflict-free, A 4-way on 8 instr (~0).
//  * NCHUNK=256 -> 4 chunks: X re-fetched 4x (was 8x), half the epilogue merges.
// The per-(row,code) single-accumulator ascending-k fmaf chain is unchanged
// -> distances remain bit-exact vs the CPU BLAS reference.
__global__ __launch_bounds__(256,2) void fused_argmin_kernel(
    const float* __restrict__ X, const float* __restrict__ CB,
    const float* __restrict__ xsq, const float* __restrict__ csq,
    float* __restrict__ hist, float* __restrict__ acc_sc,
    float* __restrict__ out)
{
  __shared__ float As[KC][SA];
  __shared__ float Bs[KC][SB];
  __shared__ int   sk[MT];          // argmin index broadcast for the gather phase
  const int t  = threadIdx.x;
  const int tx = t & 15, ty = t >> 4;     // ty 0..15
  const int m0 = blockIdx.x * MT;

  // per-thread online state for rows ty*4 + {0..3}
  float dm[4]; int km[4]; float Ss[4], Ts[4];

  float4 xs4 = *(const float4*)(xsq + m0 + ty*4);
  float xs_[4] = {xs4.x, xs4.y, xs4.z, xs4.w};

  const int arow = t >> 2;            // 0..63 : row within tile
  const int acol = (t & 3) * 8;       // 0,8,16,24 : k offset (8 floats per thread)
  const float* Ag = X + (size_t)(m0 + arow)*DIMS + acol;

  // stage-0 register prefetch (nc=0, kc=0)
  float4 a4p[2], b4p[8];
  a4p[0] = *(const float4*)(Ag);
  a4p[1] = *(const float4*)(Ag + 4);
  {
    const float* Bg = CB + (size_t)t*DIMS;   // code t of chunk 0
    #pragma unroll
    for(int q=0;q<8;q++) b4p[q] = *(const float4*)(Bg + q*4);
  }

  for(int nc=0; nc<4; nc++){
    const int n0c = nc*NCHUNK;
    float acc[4][16];
    #pragma unroll
    for(int i=0;i<4;i++)
      #pragma unroll
      for(int j=0;j<16;j++) acc[i][j]=0.f;

    // K-chain: strictly ascending k=0..255, one fmaf chain per (row,code)
    for(int kc=0;kc<8;kc++){
      __syncthreads();
      // commit prefetched stage to LDS (k-major scatter)
      #pragma unroll
      for(int q=0;q<2;q++){
        As[acol+q*4+0][arow]=a4p[q].x; As[acol+q*4+1][arow]=a4p[q].y;
        As[acol+q*4+2][arow]=a4p[q].z; As[acol+q*4+3][arow]=a4p[q].w;
      }
      #pragma unroll
      for(int q=0;q<8;q++){
        Bs[q*4+0][t]=b4p[q].x; Bs[q*4+1][t]=b4p[q].y;
        Bs[q*4+2][t]=b4p[q].z; Bs[q*4+3][t]=b4p[q].w;
      }
      __syncthreads();
      // prefetch next stage; latency hides under the 2048-FMA compute phase
      {
        int nkc = kc+1, nnc = nc;
        if(nkc==8){ nkc=0; nnc=(nc+1)&3; }
        const float* An = Ag + nkc*KC;
        const float* Bn = CB + (size_t)(nnc*NCHUNK + t)*DIMS + nkc*KC;
        a4p[0]=*(const float4*)(An); a4p[1]=*(const float4*)(An+4);
        #pragma unroll
        for(int q=0;q<8;q++) b4p[q]=*(const float4*)(Bn + q*4);
      }
      #pragma unroll
      for(int k=0;k<KC;k++){
        float4 av = *(const float4*)&As[k][ty*4];
        float4 b0 = *(const float4*)&Bs[k][tx*4];
        float4 b1 = *(const float4*)&Bs[k][64  + tx*4];
        float4 b2 = *(const float4*)&Bs[k][128 + tx*4];
        float4 b3 = *(const float4*)&Bs[k][192 + tx*4];
        float a_[4]={av.x,av.y,av.z,av.w};
        float b_[16]={b0.x,b0.y,b0.z,b0.w, b1.x,b1.y,b1.z,b1.w,
                      b2.x,b2.y,b2.z,b2.w, b3.x,b3.y,b3.z,b3.w};
        #pragma unroll
        for(int r=0;r<4;r++)
          #pragma unroll
          for(int j=0;j<16;j++)
            acc[r][j] = fmaf(a_[r], b_[j], acc[r][j]);
      }
    }

    // ---- chunk epilogue: d = sqrt(max(fl(fl(xs+cs) - 2*dot), 0)) -----------
    float csv[16];
    #pragma unroll
    for(int g=0;g<4;g++){
      float4 c4 = *(const float4*)(csq + n0c + g*64 + tx*4);
      csv[g*4+0]=c4.x; csv[g*4+1]=c4.y; csv[g*4+2]=c4.z; csv[g*4+3]=c4.w;
    }
    #pragma unroll
    for(int i=0;i<4;i++){
      float xs = xs_[i];
      float d[16];
      #pragma unroll
      for(int j=0;j<16;j++){
        // contraction-safe: 2*acc exact, fl(t - 2*acc)
        float d2 = (xs + csv[j]) - 2.0f*acc[i][j];
        d[j] = sqrtf(fmaxf(d2, 0.f));
      }
      // thread-local argmin, ascending kidx, strict < (first-occurrence tie)
      float dl = INFINITY; int kl = 0;
      #pragma unroll
      for(int j=0;j<16;j++){
        int kidx = n0c + (j>>2)*64 + tx*4 + (j&3);   // ascending in j
        if(d[j] < dl){ dl = d[j]; kl = kidx; }
      }
      // butterfly across the 16 tx lanes of this row group
      #pragma unroll
      for(int off=1; off<16; off<<=1){
        float od = __shfl_xor(dl, off, 64);
        int   ok = __shfl_xor(kl, off, 64);
        if(od < dl || (od == dl && ok < kl)){ dl = od; kl = ok; }
      }
      // chunk softmax stats shifted at chunk min: l = (dl - d)*100 <= 0
      float s1=0.f, t2s=0.f;
      #pragma unroll
      for(int j=0;j<16;j++){
        float l = (dl - d[j])*100.0f;
        float e = expf(l);
        s1 += e; t2s = fmaf(e, l, t2s);
      }
      #pragma unroll
      for(int off=1; off<16; off<<=1){
        s1  += __shfl_xor(s1,  off, 64);
        t2s += __shfl_xor(t2s, off, 64);
      }
      if(nc == 0){
        dm[i]=dl; km[i]=kl; Ss[i]=s1; Ts[i]=t2s;
      } else {
        if(dl < dm[i]){                      // strict <: tie keeps old (smaller idx)
          float del = 100.0f*(dl - dm[i]); float al = expf(del);
          Ts[i] = al*(Ts[i] + Ss[i]*del) + t2s;
          Ss[i] = al*Ss[i] + s1;
          dm[i] = dl; km[i] = kl;
        } else {
          float del = 100.0f*(dm[i] - dl); float al = expf(del);
          Ts[i] += al*(t2s + s1*del);
          Ss[i] += al*s1;
        }
      }
    }
  }

  // ---- final per-row writes (one owner thread per row group: tx==0)
  float plogp = 0.f;
  if(tx == 0){
    #pragma unroll
    for(int i=0;i<4;i++){
      int n = m0 + ty*4 + i;
      out[IDX_OFF + n] = (float)km[i];
      sk[ty*4 + i] = km[i];
      atomicAdd(hist + km[i], 1.0f);
      plogp += Ts[i]/Ss[i] - logf(Ss[i]);
    }
  }
  plogp = wsum64(plogp);
  if((t & 63) == 0) atomicAdd(acc_sc + 1, plogp);

  // ---- fused quant gather + mse -------------------------------------------
  __syncthreads();                 // sk[] visible to all waves
  {
    int w = t>>6, lane = t&63;
    int row0 = w*16;
    float mse = 0.f;
    #pragma unroll
    for(int r=0;r<16;r++){
      int n = m0 + row0 + r;
      int k = sk[row0 + r];
      float4 cb4 = *(const float4*)(CB + (size_t)k*DIMS + lane*4);
      float4 x4  = *(const float4*)(X  + (size_t)n*DIMS + lane*4);
      float e0=x4.x-cb4.x, e1=x4.y-cb4.y, e2=x4.z-cb4.z, e3=x4.w-cb4.w;
      mse += e0*e0 + e1*e1 + e2*e2 + e3*e3;
      *reinterpret_cast<float4*>(out + (size_t)n*DIMS + lane*4) = cb4;
    }
    mse = wsum64(mse);
    if(lane==0) atomicAdd(acc_sc+0, mse);
  }
}

// ---------------- finalize scalars (float32) --------------------------------
__global__ __launch_bounds__(256) void finalize_kernel(const float* __restrict__ hist,
                                                       const float* __restrict__ acc_sc,
                                                       float* __restrict__ out){
  __shared__ float red[256];
  int t = threadIdx.x;
  float s = 0.f;
  #pragma unroll
  for(int c=0;c<4;c++){
    float ap = hist[c*256 + t] * (1.0f/32768.0f);   // avg_probs ~ argmin histogram
    s += ap * logf(ap + 1e-5f);
  }
  red[t] = s; __syncthreads();
  for(int off=128; off; off>>=1){
    if(t<off) red[t]+=red[t+off];
    __syncthreads();
  }
  if(t==0){
    float avg_entropy    = -red[0];
    float mse            = acc_sc[0] * (1.0f/8388608.0f);
    float sample_entropy = -(acc_sc[1] * (1.0f/32768.0f));
    float commit = 0.5f*mse*0.25f;
    float cbl    = 0.5f*mse;
    float ent    = (sample_entropy - avg_entropy)*0.1f;
    float vq     = cbl + commit + ent;
    out[SC_OFF+0] = vq;
    out[SC_OFF+1] = commit;
    out[SC_OFF+2] = cbl;
    out[SC_OFF+3] = ent;
  }
}

extern "C" void kernel_launch(void* const* d_in, const int* in_sizes, int n_in,
                              void* d_out, int out_size, void* d_ws, size_t ws_size,
                              hipStream_t stream){
  const float* X  = (const float*)d_in[0];
  const float* CB = (const float*)d_in[1];
  float* out = (float*)d_out;                        // float32 output buffer
  float* xsq     = (float*)d_ws + N_ROWS;            // [32768]
  float* csq     = xsq + N_ROWS;                     // [1024]
  float* hist    = csq + K_CODES;                    // [1024]
  float* acc_sc  = hist + K_CODES;                   // [2]: mse, plogp

  hipMemsetAsync(hist, 0, (K_CODES+2)*sizeof(float), stream);
  rowsq_np512_kernel <<<(K_CODES+N_ROWS+255)/256, 256, 0, stream>>>(X, CB, xsq, csq);
  fused_argmin_kernel<<<N_ROWS/MT, 256, 0, stream>>>(X, CB, xsq, csq, hist, acc_sc, out);
  finalize_kernel    <<<1, 256, 0, stream>>>(hist, acc_sc, out);
}